// Round 5
// baseline (757.393 us; speedup 1.0000x reference)
//
#include <hip/hip_runtime.h>
#include <hip/hip_bf16.h>

typedef __bf16 bf16;
typedef __attribute__((ext_vector_type(8))) __bf16 bf16x8;
typedef __attribute__((ext_vector_type(4))) float f32x4;

constexpr int D_IN  = 512;
constexpr int D_HID = 256;
constexpr int D_OUT = 32;
constexpr int BM = 64;     // rows per block (MLP)
constexpr int BK = 32;     // K chunk (one 16x16x32 MFMA deep)
constexpr int HPAD = 260;  // see R4: 130 dwords = 2 mod 32, conflict-free epilogue
constexpr int BROWS = 128;     // rows per bucket (row >> 7)
constexpr int CHUNK = 4096;    // edges per binB chunk
constexpr int MAXNB = 1024;    // LDS counter array size (NB <= 1024)

#define GLOBAL_AS(p) ((const __attribute__((address_space(1))) void*)(p))
#define LDS_AS(p)    ((__attribute__((address_space(3))) void*)(p))

// ---------------- prep: W1 -> W1T (bf16, [n][k]), W2 -> W2T (bf16, [n][k]) --
__global__ __launch_bounds__(256) void prep_kernel(
    const float* __restrict__ W1, const float* __restrict__ W2,
    bf16* __restrict__ W1T, bf16* __restrict__ W2T)
{
    int idx = blockIdx.x * 256 + threadIdx.x;
    if (idx < D_IN * D_HID) {
        int k = idx / D_HID, n = idx % D_HID;
        W1T[n * D_IN + k] = (bf16)W1[idx];
    }
    int j = idx - D_IN * D_HID;
    if (j >= 0 && j < D_HID * D_OUT) {
        int k = j / D_OUT, n = j % D_OUT;
        W2T[n * D_HID + k] = (bf16)W2[j];
    }
}

// ---------------- fused MLP: X = relu(feat@W1 + b1) @ W2 + b2 ---------------
__global__ __launch_bounds__(256) void fused_mlp_kernel(
    const float* __restrict__ feat,
    const bf16* __restrict__ W1T, const bf16* __restrict__ W2T,
    const float* __restrict__ b1, const float* __restrict__ b2,
    float* __restrict__ X, int N)
{
    __shared__ __align__(16) char smem[(BM + D_OUT) * HPAD * sizeof(bf16)];
    bf16* Asm  = (bf16*)smem;                         // [BM][BK]
    bf16* Bsm  = (bf16*)(smem + BM * BK * 2);         // [D_HID][BK]
    bf16* Hsm  = (bf16*)smem;                         // [BM][HPAD] (aliases staging)
    bf16* B2sm = (bf16*)(smem + BM * HPAD * 2);       // [D_OUT][HPAD]

    const int tid  = threadIdx.x;
    const int wave = tid >> 6;
    const int lane = tid & 63;
    const int ln   = lane & 15;
    const int q    = lane >> 4;
    const int mw   = wave * 16;
    const int r0   = blockIdx.x * BM;

    #pragma unroll
    for (int i = 0; i < 4; ++i) {
        int c  = tid + i * 256;
        int n  = c >> 5;
        int kc = (c & 31) * 8;
        *(bf16x8*)&B2sm[n * HPAD + kc] = *(const bf16x8*)&W2T[n * D_HID + kc];
    }

    f32x4 acc[16] = {};

    const int am   = tid >> 2;
    const int asub = (tid & 3) * 8;
    const long arow = (long)min(r0 + am, N - 1);
    const float* asrc = feat + arow * D_IN + asub;

    for (int k0 = 0; k0 < D_IN; k0 += BK) {
        #pragma unroll
        for (int i = 0; i < 4; ++i) {
            int c = i * 256 + wave * 64 + lane;
            const bf16* gsrc = W1T + ((c >> 2) * D_IN + k0 + (c & 3) * 8);
            bf16* lbase = Bsm + (i * 256 + wave * 64) * 8;  // wave-uniform
            __builtin_amdgcn_global_load_lds(GLOBAL_AS(gsrc), LDS_AS(lbase), 16, 0, 0);
        }

        float4 f0 = *(const float4*)(asrc + k0);
        float4 f1 = *(const float4*)(asrc + k0 + 4);
        bf16x8 av;
        av[0] = (bf16)f0.x; av[1] = (bf16)f0.y; av[2] = (bf16)f0.z; av[3] = (bf16)f0.w;
        av[4] = (bf16)f1.x; av[5] = (bf16)f1.y; av[6] = (bf16)f1.z; av[7] = (bf16)f1.w;
        *(bf16x8*)&Asm[am * BK + asub] = av;

        __syncthreads();

        bf16x8 af = *(const bf16x8*)&Asm[(mw + ln) * BK + q * 8];
        #pragma unroll
        for (int t = 0; t < 16; ++t) {
            bf16x8 bf = *(const bf16x8*)&Bsm[(t * 16 + ln) * BK + q * 8];
            acc[t] = __builtin_amdgcn_mfma_f32_16x16x32_bf16(af, bf, acc[t], 0, 0, 0);
        }
        __syncthreads();
    }

    #pragma unroll
    for (int t = 0; t < 16; ++t) {
        int colh = t * 16 + ln;
        float bb = b1[colh];
        #pragma unroll
        for (int i = 0; i < 4; ++i) {
            int row = mw + q * 4 + i;
            float v = acc[t][i] + bb;
            Hsm[row * HPAD + colh] = (bf16)fmaxf(v, 0.0f);
        }
    }
    __syncthreads();

    f32x4 acc2[2] = {};
    #pragma unroll
    for (int k0 = 0; k0 < D_HID; k0 += BK) {
        bf16x8 af = *(const bf16x8*)&Hsm[(mw + ln) * HPAD + k0 + q * 8];
        #pragma unroll
        for (int t = 0; t < 2; ++t) {
            bf16x8 bf = *(const bf16x8*)&B2sm[(t * 16 + ln) * HPAD + k0 + q * 8];
            acc2[t] = __builtin_amdgcn_mfma_f32_16x16x32_bf16(af, bf, acc2[t], 0, 0, 0);
        }
    }

    #pragma unroll
    for (int t = 0; t < 2; ++t) {
        int c = t * 16 + ln;
        float bb = b2[c];
        #pragma unroll
        for (int i = 0; i < 4; ++i) {
            int row = r0 + mw + q * 4 + i;
            if (row < N) X[row * D_OUT + c] = acc2[t][i] + bb;
        }
    }
}

// ---------------- binA: LDS-aggregated bucket histogram ---------------------
__global__ __launch_bounds__(256) void binA_kernel(
    const int* __restrict__ Arow, int* __restrict__ bcnt, int E, int NB)
{
    __shared__ int c[MAXNB];
    int tid = threadIdx.x;
    for (int i = tid; i < MAXNB; i += 256) c[i] = 0;
    __syncthreads();
    for (int e = blockIdx.x * 256 + tid; e < E; e += gridDim.x * 256)
        atomicAdd(&c[Arow[e] >> 7], 1);
    __syncthreads();
    for (int b = tid; b < NB; b += 256)
        if (c[b]) atomicAdd(&bcnt[b], c[b]);
}

// ---------------- scanS: single-block exclusive scan of NB counts -----------
__global__ __launch_bounds__(256) void scanS_kernel(
    const int* __restrict__ bcnt, int* __restrict__ boff,
    int* __restrict__ bcur, int NB)
{
    __shared__ int lds[256];
    int t = threadIdx.x;
    int v[4];
    int tsum = 0;
    #pragma unroll
    for (int j = 0; j < 4; ++j) {
        int idx = t * 4 + j;
        v[j] = (idx < NB) ? bcnt[idx] : 0;
        tsum += v[j];
    }
    lds[t] = tsum;
    __syncthreads();
    for (int d = 1; d < 256; d <<= 1) {
        int x = (t >= d) ? lds[t - d] : 0;
        __syncthreads();
        lds[t] += x;
        __syncthreads();
    }
    int run = lds[t] - tsum;
    #pragma unroll
    for (int j = 0; j < 4; ++j) {
        int idx = t * 4 + j;
        if (idx < NB) { boff[idx] = run; bcur[idx] = run; }
        run += v[j];
    }
}

// ---------------- binB: chunked range-reservation scatter into buckets ------
// pairs[p].x = col | (rowoff << 17)   (needs N <= 2^17, BROWS=128 -> 7 bits)
// pairs[p].y = bits of A_data
__global__ __launch_bounds__(256) void binB_kernel(
    const int* __restrict__ Arow, const int* __restrict__ Acol,
    const float* __restrict__ Adata, int* __restrict__ bcur,
    int2* __restrict__ pairs, int E, int NB)
{
    __shared__ int cnt[MAXNB];
    __shared__ int pos[MAXNB];
    int tid = threadIdx.x;
    int nch = (E + CHUNK - 1) / CHUNK;
    for (int ch = blockIdx.x; ch < nch; ch += gridDim.x) {
        int base = ch * CHUNK;
        for (int i = tid; i < MAXNB; i += 256) cnt[i] = 0;
        __syncthreads();
        #pragma unroll
        for (int k = 0; k < CHUNK / 256; ++k) {
            int e = base + k * 256 + tid;
            if (e < E) atomicAdd(&cnt[Arow[e] >> 7], 1);
        }
        __syncthreads();
        for (int b = tid; b < NB; b += 256) {
            int c = cnt[b];
            if (c) pos[b] = atomicAdd(&bcur[b], c);
        }
        __syncthreads();
        #pragma unroll
        for (int k = 0; k < CHUNK / 256; ++k) {
            int e = base + k * 256 + tid;
            if (e < E) {
                int r = Arow[e];
                int b = r >> 7;
                int p = atomicAdd(&pos[b], 1);
                int2 pk;
                pk.x = Acol[e] | ((r & 127) << 17);
                pk.y = __float_as_int(Adata[e]);
                pairs[p] = pk;
            }
        }
        __syncthreads();
    }
}

// ---------------- binC: per-bucket LDS-accumulated reduce -------------------
__global__ __launch_bounds__(256) void binC_kernel(
    const int* __restrict__ boff, const int* __restrict__ bcnt,
    const int2* __restrict__ pairs, const float* __restrict__ X,
    float* __restrict__ out, int N)
{
    __shared__ float acc[BROWS * D_OUT];   // 16 KB
    int tid = threadIdx.x;
    for (int i = tid; i < BROWS * D_OUT / 4; i += 256)
        *(f32x4*)&acc[i * 4] = (f32x4){0.0f, 0.0f, 0.0f, 0.0f};
    __syncthreads();

    int b   = blockIdx.x;
    int off = boff[b];
    int cnt = bcnt[b];
    int slot = tid >> 3;   // 0..31 edge slots
    int dg   = tid & 7;    // dims 4*dg..4*dg+3

    for (int i = slot; i < cnt; i += 64) {
        int2 p1 = pairs[off + i];
        bool h2 = (i + 32) < cnt;
        int2 p2 = h2 ? pairs[off + i + 32] : p1;
        int   c1 = p1.x & 0x1FFFF, r1 = (p1.x >> 17) & 127;
        float a1 = __int_as_float(p1.y);
        int   c2 = p2.x & 0x1FFFF, r2 = (p2.x >> 17) & 127;
        float a2 = __int_as_float(p2.y);
        f32x4 x1 = *(const f32x4*)(X + (long)c1 * D_OUT + dg * 4);
        f32x4 x2 = *(const f32x4*)(X + (long)c2 * D_OUT + dg * 4);
        f32x4 m1 = a1 * x1;
        #pragma unroll
        for (int j = 0; j < 4; ++j) atomicAdd(&acc[r1 * D_OUT + dg * 4 + j], m1[j]);
        if (h2) {
            f32x4 m2 = a2 * x2;
            #pragma unroll
            for (int j = 0; j < 4; ++j) atomicAdd(&acc[r2 * D_OUT + dg * 4 + j], m2[j]);
        }
    }
    __syncthreads();

    long rbase = (long)b * BROWS;
    #pragma unroll
    for (int k = 0; k < 4; ++k) {
        int idx = k * 1024 + tid * 4;       // float index into acc
        int row = idx >> 5;                 // /32
        if (rbase + row < N)
            *(f32x4*)(out + rbase * D_OUT + idx) = *(f32x4*)&acc[idx];
    }
}

// ---------------- fallback scatter (if ws too small / N too big) ------------
__global__ __launch_bounds__(256) void scatter_kernel(
    const float* __restrict__ Adata, const int* __restrict__ Arow,
    const int* __restrict__ Acol, const float* __restrict__ X,
    float* __restrict__ out, int E)
{
    int idx = blockIdx.x * 256 + threadIdx.x;
    int e = idx >> 3;
    int g = idx & 7;
    if (e >= E) return;
    int   col = Acol[e];
    int   row = Arow[e];
    float a   = Adata[e];
    float4 x = *(const float4*)(X + (long)col * D_OUT + g * 4);
    float* o = out + (long)row * D_OUT + g * 4;
    unsafeAtomicAdd(o + 0, a * x.x);
    unsafeAtomicAdd(o + 1, a * x.y);
    unsafeAtomicAdd(o + 2, a * x.z);
    unsafeAtomicAdd(o + 3, a * x.w);
}

// ---------------- launch ----------------------------------------------------
extern "C" void kernel_launch(void* const* d_in, const int* in_sizes, int n_in,
                              void* d_out, int out_size, void* d_ws, size_t ws_size,
                              hipStream_t stream)
{
    const float* feat  = (const float*)d_in[0];
    const float* Adata = (const float*)d_in[1];
    const float* W1    = (const float*)d_in[2];
    const float* b1    = (const float*)d_in[3];
    const float* W2    = (const float*)d_in[4];
    const float* b2    = (const float*)d_in[5];
    const int*   Arow  = (const int*)d_in[6];
    const int*   Acol  = (const int*)d_in[7];

    const int N = in_sizes[0] / D_IN;
    const int E = in_sizes[1];
    const int NB = (N + BROWS - 1) / BROWS;

    char* p = (char*)d_ws;
    auto alloc = [&](size_t bytes) {
        char* q = p;
        p += (bytes + 255) & ~(size_t)255;
        return q;
    };
    float* X    = (float*)alloc((size_t)N * D_OUT * sizeof(float));
    bf16*  W1T  = (bf16*) alloc((size_t)D_IN * D_HID * sizeof(bf16));
    bf16*  W2T  = (bf16*) alloc((size_t)D_HID * D_OUT * sizeof(bf16));
    int*   bcnt = (int*)  alloc((size_t)NB * sizeof(int));
    int*   boff = (int*)  alloc((size_t)NB * sizeof(int));
    int*   bcur = (int*)  alloc((size_t)NB * sizeof(int));
    int2*  pairs= (int2*) alloc((size_t)E * sizeof(int2));
    size_t need = (size_t)(p - (char*)d_ws);
    const bool use_csr = (need <= ws_size) && (N <= (1 << 17)) && (NB <= MAXNB);

    float* out = (float*)d_out;

    int prep_elems = D_IN * D_HID + D_HID * D_OUT;
    prep_kernel<<<(prep_elems + 255) / 256, 256, 0, stream>>>(W1, W2, W1T, W2T);

    fused_mlp_kernel<<<(N + BM - 1) / BM, 256, 0, stream>>>(
        feat, W1T, W2T, b1, b2, X, N);

    if (use_csr) {
        hipMemsetAsync(bcnt, 0, (size_t)NB * sizeof(int), stream);
        binA_kernel<<<256, 256, 0, stream>>>(Arow, bcnt, E, NB);
        scanS_kernel<<<1, 256, 0, stream>>>(bcnt, boff, bcur, NB);
        binB_kernel<<<200, 256, 0, stream>>>(Arow, Acol, Adata, bcur, pairs, E, NB);
        binC_kernel<<<NB, 256, 0, stream>>>(boff, bcnt, pairs, X, out, N);
    } else {
        hipMemsetAsync(out, 0, (size_t)out_size * sizeof(float), stream);
        long scatter_threads = (long)E * 8;
        scatter_kernel<<<(scatter_threads + 255) / 256, 256, 0, stream>>>(
            Adata, Arow, Acol, X, out, E);
    }
}